// Round 2
// baseline (13596.463 us; speedup 1.0000x reference)
//
#include <hip/hip_runtime.h>

#define F 128          // feature dim
#define F4 32          // feature dim in float4
#define SCAN_CHUNK 1024

// ---------- zero int buffer ----------
__global__ void k_zero_int(int* p, int n) {
    int i = blockIdx.x * blockDim.x + threadIdx.x;
    if (i < n) p[i] = 0;
}

// ---------- histogram of dst ----------
__global__ void k_hist(const int* __restrict__ dst, int* cnt, int e) {
    int i = blockIdx.x * blockDim.x + threadIdx.x;
    if (i < e) atomicAdd(&cnt[dst[i]], 1);
}

// ---------- dinv[v] = 1/sqrt(cnt[v] + 1)  (self-loop) ----------
__global__ void k_rsqrt(const int* __restrict__ cnt, float* dinv, int n) {
    int i = blockIdx.x * blockDim.x + threadIdx.x;
    if (i < n) dinv[i] = 1.0f / sqrtf((float)cnt[i] + 1.0f);
}

// ---------- exclusive scan of cnt[0..n) -> rowptr[0..n), 3-phase ----------
__global__ void k_scan1(const int* __restrict__ cnt, int* rowptr, int* bsum, int n) {
    __shared__ int s[SCAN_CHUNK];
    int base = blockIdx.x * SCAN_CHUNK;
    int tid = threadIdx.x;
    for (int t = tid; t < SCAN_CHUNK; t += 256)
        s[t] = (base + t < n) ? cnt[base + t] : 0;
    __syncthreads();
    for (int off = 1; off < SCAN_CHUNK; off <<= 1) {
        int v0 = (tid       >= off) ? s[tid       - off] : 0;
        int v1 = (tid + 256 >= off) ? s[tid + 256 - off] : 0;
        int v2 = (tid + 512 >= off) ? s[tid + 512 - off] : 0;
        int v3 = (tid + 768 >= off) ? s[tid + 768 - off] : 0;
        __syncthreads();
        s[tid      ] += v0;
        s[tid + 256] += v1;
        s[tid + 512] += v2;
        s[tid + 768] += v3;
        __syncthreads();
    }
    // exclusive = inclusive - self
    for (int t = tid; t < SCAN_CHUNK; t += 256)
        if (base + t < n) rowptr[base + t] = s[t] - cnt[base + t];
    if (tid == 0) bsum[blockIdx.x] = s[SCAN_CHUNK - 1];
}

__global__ void k_scan2(int* bsum, int nb) {
    __shared__ int s[128];
    int tid = threadIdx.x;
    int v = (tid < nb) ? bsum[tid] : 0;
    s[tid] = v;
    __syncthreads();
    for (int off = 1; off < 128; off <<= 1) {
        int u = (tid >= off) ? s[tid - off] : 0;
        __syncthreads();
        s[tid] += u;
        __syncthreads();
    }
    if (tid < nb) bsum[tid] = s[tid] - v;   // exclusive
}

__global__ void k_scan3(int* rowptr, const int* __restrict__ bsum, int n, int e) {
    int base = blockIdx.x * SCAN_CHUNK;
    int add = bsum[blockIdx.x];
    for (int t = threadIdx.x; t < SCAN_CHUNK; t += 256)
        if (base + t < n) rowptr[base + t] += add;
    if (blockIdx.x == 0 && threadIdx.x == 0) rowptr[n] = e;
}

// ---------- fill CSR: col (src ids) + per-edge norm, bucketed by dst ----------
__global__ void k_fill(const int* __restrict__ src, const int* __restrict__ dst,
                       const int* __restrict__ rowptr, int* cursor,
                       const float* __restrict__ dinv,
                       int* col, float* enorm, int e) {
    int i = blockIdx.x * blockDim.x + threadIdx.x;
    if (i >= e) return;
    int d = dst[i];
    int s = src[i];
    int pos = rowptr[d] + atomicAdd(&cursor[d], 1);
    col[pos] = s;
    enorm[pos] = dinv[s] * dinv[d];
}

// ---------- dense matmul: H[n,128] = X[n,128] @ W[128,128], 8 rows/block ----------
__global__ void k_matmul8(const float* __restrict__ X, const float* __restrict__ W,
                          float* __restrict__ H, int n) {
    __shared__ float xs[8][F];
    int row0 = blockIdx.x * 8;
    int tid = threadIdx.x;
    for (int t = tid; t < 8 * F; t += 256) {
        int r = t >> 7, c = t & (F - 1);
        xs[r][c] = (row0 + r < n) ? X[(size_t)(row0 + r) * F + c] : 0.f;
    }
    __syncthreads();
    int j = tid & (F - 1);
    int rh = (tid >> 7) * 4;   // 0 or 4
    float a0 = 0.f, a1 = 0.f, a2 = 0.f, a3 = 0.f;
#pragma unroll
    for (int k = 0; k < F; ++k) {
        float w = W[k * F + j];
        a0 = fmaf(xs[rh + 0][k], w, a0);
        a1 = fmaf(xs[rh + 1][k], w, a1);
        a2 = fmaf(xs[rh + 2][k], w, a2);
        a3 = fmaf(xs[rh + 3][k], w, a3);
    }
    if (row0 + rh + 0 < n) H[(size_t)(row0 + rh + 0) * F + j] = a0;
    if (row0 + rh + 1 < n) H[(size_t)(row0 + rh + 1) * F + j] = a1;
    if (row0 + rh + 2 < n) H[(size_t)(row0 + rh + 2) * F + j] = a2;
    if (row0 + rh + 3 < n) H[(size_t)(row0 + rh + 3) * F + j] = a3;
}

// ---------- fused aggregate: out = relu(selfloop + gather + bias) ----------
// 8 nodes per 256-thread block, 32 lanes (float4) per node
__global__ void k_aggregate(const float4* __restrict__ H4,
                            const int* __restrict__ rowptr,
                            const int* __restrict__ col,
                            const float* __restrict__ enorm,
                            const float* __restrict__ dinv,
                            const float4* __restrict__ b4,
                            float4* __restrict__ out4, int n) {
    int v = blockIdx.x * 8 + (threadIdx.x >> 5);
    int lane = threadIdx.x & 31;
    if (v >= n) return;
    float dv = dinv[v];
    float sl = dv * dv;
    float4 acc = H4[(size_t)v * F4 + lane];
    acc.x *= sl; acc.y *= sl; acc.z *= sl; acc.w *= sl;
    int beg = rowptr[v], end = rowptr[v + 1];
    for (int j = beg; j < end; ++j) {
        int s = col[j];
        float w = enorm[j];
        float4 hv = H4[(size_t)s * F4 + lane];
        acc.x = fmaf(hv.x, w, acc.x);
        acc.y = fmaf(hv.y, w, acc.y);
        acc.z = fmaf(hv.z, w, acc.z);
        acc.w = fmaf(hv.w, w, acc.w);
    }
    float4 bb = b4[lane];
    acc.x = fmaxf(acc.x + bb.x, 0.f);
    acc.y = fmaxf(acc.y + bb.y, 0.f);
    acc.z = fmaxf(acc.z + bb.z, 0.f);
    acc.w = fmaxf(acc.w + bb.w, 0.f);
    out4[(size_t)v * F4 + lane] = acc;
}

// ---------- mean pool ----------
__global__ void k_zero128(float* p) { p[threadIdx.x] = 0.f; }

__global__ void k_pool(const float* __restrict__ H, float* pooled, int n, float inv_n) {
    int f = threadIdx.x & (F - 1);
    int rowoff = threadIdx.x >> 7;
    float s = 0.f;
    for (int row = blockIdx.x * 2 + rowoff; row < n; row += gridDim.x * 2)
        s += H[(size_t)row * F + f];
    __shared__ float sm[256];
    sm[threadIdx.x] = s;
    __syncthreads();
    if (threadIdx.x < F)
        atomicAdd(&pooled[f], (sm[threadIdx.x] + sm[threadIdx.x + F]) * inv_n);
}

// ---------- final FC ----------
__global__ void k_fc(const float* __restrict__ pooled, const float* __restrict__ fcw,
                     const float* __restrict__ fcb, float* out) {
    __shared__ float sm[2 * F];
    int f = threadIdx.x;
    float p = pooled[f];
    sm[f]     = p * fcw[f * 2 + 0];
    sm[f + F] = p * fcw[f * 2 + 1];
    __syncthreads();
    for (int off = 64; off > 0; off >>= 1) {
        if (f < off) {
            sm[f]     += sm[f + off];
            sm[F + f] += sm[F + f + off];
        }
        __syncthreads();
    }
    if (f == 0) {
        out[0] = sm[0] + fcb[0];
        out[1] = sm[F] + fcb[1];
    }
}

extern "C" void kernel_launch(void* const* d_in, const int* in_sizes, int n_in,
                              void* d_out, int out_size, void* d_ws, size_t ws_size,
                              hipStream_t stream) {
    const float* x   = (const float*)d_in[0];
    const int*   ei  = (const int*)  d_in[1];
    const float* W1  = (const float*)d_in[2];
    const float* b1  = (const float*)d_in[3];
    const float* W2  = (const float*)d_in[4];
    const float* b2  = (const float*)d_in[5];
    const float* W3  = (const float*)d_in[6];
    const float* b3  = (const float*)d_in[7];
    const float* fcw = (const float*)d_in[8];
    const float* fcb = (const float*)d_in[9];
    float* out = (float*)d_out;

    const int n = in_sizes[0] / F;     // 100000
    const int e = in_sizes[1] / 2;     // 1600000
    const int* src = ei;
    const int* dst = ei + e;

    // workspace layout (all chunks multiple-of-4 floats => 16B aligned)
    float* ws     = (float*)d_ws;
    float* dinv   = ws;                         // n
    float* pooled = dinv + n;                   // 128
    int*   rowptr = (int*)(pooled + 128);       // n+4 (padded)
    int*   cnt    = rowptr + (n + 4);           // n   (also cursor)
    int*   bsum   = cnt + n;                    // 2048
    int*   col    = bsum + 2048;                // e
    float* enorm  = (float*)(col + e);          // e
    float* bufA   = enorm + e;                  // n*F
    float* bufB   = bufA + (size_t)n * F;       // n*F

    const int BT = 256;
    dim3 blk(BT);
    int gN    = (n + BT - 1) / BT;
    int gE    = (e + BT - 1) / BT;
    int gRows = (n + 7) / 8;
    int nbScan = (n + SCAN_CHUNK - 1) / SCAN_CHUNK;   // 98

    // ---- CSR build ----
    k_zero_int<<<gN, blk, 0, stream>>>(cnt, n);
    k_hist    <<<gE, blk, 0, stream>>>(dst, cnt, e);
    k_rsqrt   <<<gN, blk, 0, stream>>>(cnt, dinv, n);
    k_scan1   <<<nbScan, blk, 0, stream>>>(cnt, rowptr, bsum, n);
    k_scan2   <<<1, dim3(128), 0, stream>>>(bsum, nbScan);
    k_scan3   <<<nbScan, blk, 0, stream>>>(rowptr, bsum, n, e);
    k_zero_int<<<gN, blk, 0, stream>>>(cnt, n);      // reuse as cursor
    k_fill    <<<gE, blk, 0, stream>>>(src, dst, rowptr, cnt, dinv, col, enorm, e);

    // ---- 3 GCN layers ----
    const float* layer_in = x;
    const float* Ws[3] = {W1, W2, W3};
    const float* bs[3] = {b1, b2, b3};
    for (int l = 0; l < 3; ++l) {
        k_matmul8<<<gRows, blk, 0, stream>>>(layer_in, Ws[l], bufB, n);
        k_aggregate<<<gRows, blk, 0, stream>>>((const float4*)bufB, rowptr, col, enorm,
                                               dinv, (const float4*)bs[l],
                                               (float4*)bufA, n);
        layer_in = bufA;
    }

    // ---- mean pool + FC ----
    k_zero128<<<1, dim3(F), 0, stream>>>(pooled);
    k_pool   <<<512, blk, 0, stream>>>(bufA, pooled, n, 1.0f / (float)n);
    k_fc     <<<1, dim3(F), 0, stream>>>(pooled, fcw, fcb, out);
}

// Round 3
// 928.093 us; speedup vs baseline: 14.6499x; 14.6499x over previous
//
#include <hip/hip_runtime.h>

#define F 128          // feature dim
#define F4 32          // feature dim in float4
#define SCAN_CHUNK 1024
#define MM_ROWS 16     // rows per matmul block

// ---------- zero int buffer ----------
__global__ void k_zero_int(int* p, int n) {
    int i = blockIdx.x * blockDim.x + threadIdx.x;
    if (i < n) p[i] = 0;
}

// ---------- histogram of dst ----------
__global__ void k_hist(const int* __restrict__ dst, int* cnt, int e) {
    int i = blockIdx.x * blockDim.x + threadIdx.x;
    if (i < e) atomicAdd(&cnt[dst[i]], 1);
}

// ---------- dinv[v] = 1/sqrt(cnt[v] + 1)  (self-loop) ----------
__global__ void k_rsqrt(const int* __restrict__ cnt, float* dinv, int n) {
    int i = blockIdx.x * blockDim.x + threadIdx.x;
    if (i < n) dinv[i] = 1.0f / sqrtf((float)cnt[i] + 1.0f);
}

// ---------- exclusive scan of cnt[0..n) -> rowptr[0..n), 3-phase ----------
__global__ void k_scan1(const int* __restrict__ cnt, int* rowptr, int* bsum, int n) {
    __shared__ int s[SCAN_CHUNK];
    int base = blockIdx.x * SCAN_CHUNK;
    int tid = threadIdx.x;
    for (int t = tid; t < SCAN_CHUNK; t += 256)
        s[t] = (base + t < n) ? cnt[base + t] : 0;
    __syncthreads();
    for (int off = 1; off < SCAN_CHUNK; off <<= 1) {
        int v0 = (tid       >= off) ? s[tid       - off] : 0;
        int v1 = (tid + 256 >= off) ? s[tid + 256 - off] : 0;
        int v2 = (tid + 512 >= off) ? s[tid + 512 - off] : 0;
        int v3 = (tid + 768 >= off) ? s[tid + 768 - off] : 0;
        __syncthreads();
        s[tid      ] += v0;
        s[tid + 256] += v1;
        s[tid + 512] += v2;
        s[tid + 768] += v3;
        __syncthreads();
    }
    for (int t = tid; t < SCAN_CHUNK; t += 256)
        if (base + t < n) rowptr[base + t] = s[t] - cnt[base + t];
    if (tid == 0) bsum[blockIdx.x] = s[SCAN_CHUNK - 1];
}

__global__ void k_scan2(int* bsum, int nb) {
    __shared__ int s[128];
    int tid = threadIdx.x;
    int v = (tid < nb) ? bsum[tid] : 0;
    s[tid] = v;
    __syncthreads();
    for (int off = 1; off < 128; off <<= 1) {
        int u = (tid >= off) ? s[tid - off] : 0;
        __syncthreads();
        s[tid] += u;
        __syncthreads();
    }
    if (tid < nb) bsum[tid] = s[tid] - v;   // exclusive
}

__global__ void k_scan3(int* rowptr, const int* __restrict__ bsum, int n, int e) {
    int base = blockIdx.x * SCAN_CHUNK;
    int add = bsum[blockIdx.x];
    for (int t = threadIdx.x; t < SCAN_CHUNK; t += 256)
        if (base + t < n) rowptr[base + t] += add;
    if (blockIdx.x == 0 && threadIdx.x == 0) rowptr[n] = e;
}

// ---------- fill CSR: col (src ids) + per-edge norm, bucketed by dst ----------
__global__ void k_fill(const int* __restrict__ src, const int* __restrict__ dst,
                       const int* __restrict__ rowptr, int* cursor,
                       const float* __restrict__ dinv,
                       int* col, float* enorm, int e) {
    int i = blockIdx.x * blockDim.x + threadIdx.x;
    if (i >= e) return;
    int d = dst[i];
    int s = src[i];
    int pos = rowptr[d] + atomicAdd(&cursor[d], 1);
    col[pos] = s;
    enorm[pos] = dinv[s] * dinv[d];
}

// ---------- dense matmul: H[n,128] = X[n,128] @ W[128,128] ----------
// 16 rows/block, 256 threads; thread = (column j, 8-row group).
// 8 accumulators (~30 VGPR, no spill); k stepped by 4, W as float4,
// X via LDS broadcast ds_read_b128. NO full k-unroll (spill-proof).
__global__ __launch_bounds__(256, 4)
void k_matmul16(const float* __restrict__ X, const float* __restrict__ W,
                float* __restrict__ H, int n) {
    __shared__ float xs[MM_ROWS][F];   // 8 KB
    int row0 = blockIdx.x * MM_ROWS;
    int tid = threadIdx.x;

    // stage X tile: 16*128 = 2048 floats = 512 float4; 2 per thread
    if (row0 + MM_ROWS <= n) {
        const float4* X4 = (const float4*)(X + (size_t)row0 * F);
        float4* xs4 = (float4*)xs;
        xs4[tid]       = X4[tid];
        xs4[tid + 256] = X4[tid + 256];
    } else {
        for (int t = tid; t < MM_ROWS * F; t += 256) {
            int r = t >> 7, c = t & (F - 1);
            xs[r][c] = (row0 + r < n) ? X[(size_t)(row0 + r) * F + c] : 0.f;
        }
    }
    __syncthreads();

    int j = tid & (F - 1);
    int rbase = (tid >> 7) * 8;   // 0 or 8
    float acc[8] = {0.f, 0.f, 0.f, 0.f, 0.f, 0.f, 0.f, 0.f};

    for (int k = 0; k < F; k += 4) {
        float4 w4;
        w4.x = W[(k + 0) * F + j];
        w4.y = W[(k + 1) * F + j];
        w4.z = W[(k + 2) * F + j];
        w4.w = W[(k + 3) * F + j];
#pragma unroll
        for (int r = 0; r < 8; ++r) {
            float4 xv = *(const float4*)&xs[rbase + r][k];   // broadcast b128
            acc[r] = fmaf(xv.x, w4.x, acc[r]);
            acc[r] = fmaf(xv.y, w4.y, acc[r]);
            acc[r] = fmaf(xv.z, w4.z, acc[r]);
            acc[r] = fmaf(xv.w, w4.w, acc[r]);
        }
    }

    int rowEnd = n - row0;
#pragma unroll
    for (int r = 0; r < 8; ++r) {
        if (rbase + r < rowEnd)
            H[(size_t)(row0 + rbase + r) * F + j] = acc[r];
    }
}

// ---------- fused aggregate: out = relu(selfloop + gather + bias) ----------
// 8 nodes per 256-thread block, 32 lanes (float4) per node
__global__ void k_aggregate(const float4* __restrict__ H4,
                            const int* __restrict__ rowptr,
                            const int* __restrict__ col,
                            const float* __restrict__ enorm,
                            const float* __restrict__ dinv,
                            const float4* __restrict__ b4,
                            float4* __restrict__ out4, int n) {
    int v = blockIdx.x * 8 + (threadIdx.x >> 5);
    int lane = threadIdx.x & 31;
    if (v >= n) return;
    float dv = dinv[v];
    float sl = dv * dv;
    float4 acc = H4[(size_t)v * F4 + lane];
    acc.x *= sl; acc.y *= sl; acc.z *= sl; acc.w *= sl;
    int beg = rowptr[v], end = rowptr[v + 1];
    for (int j = beg; j < end; ++j) {
        int s = col[j];
        float w = enorm[j];
        float4 hv = H4[(size_t)s * F4 + lane];
        acc.x = fmaf(hv.x, w, acc.x);
        acc.y = fmaf(hv.y, w, acc.y);
        acc.z = fmaf(hv.z, w, acc.z);
        acc.w = fmaf(hv.w, w, acc.w);
    }
    float4 bb = b4[lane];
    acc.x = fmaxf(acc.x + bb.x, 0.f);
    acc.y = fmaxf(acc.y + bb.y, 0.f);
    acc.z = fmaxf(acc.z + bb.z, 0.f);
    acc.w = fmaxf(acc.w + bb.w, 0.f);
    out4[(size_t)v * F4 + lane] = acc;
}

// ---------- mean pool ----------
__global__ void k_zero128(float* p) { p[threadIdx.x] = 0.f; }

__global__ void k_pool(const float* __restrict__ H, float* pooled, int n, float inv_n) {
    int f = threadIdx.x & (F - 1);
    int rowoff = threadIdx.x >> 7;
    float s = 0.f;
    for (int row = blockIdx.x * 2 + rowoff; row < n; row += gridDim.x * 2)
        s += H[(size_t)row * F + f];
    __shared__ float sm[256];
    sm[threadIdx.x] = s;
    __syncthreads();
    if (threadIdx.x < F)
        atomicAdd(&pooled[f], (sm[threadIdx.x] + sm[threadIdx.x + F]) * inv_n);
}

// ---------- final FC ----------
__global__ void k_fc(const float* __restrict__ pooled, const float* __restrict__ fcw,
                     const float* __restrict__ fcb, float* out) {
    __shared__ float sm[2 * F];
    int f = threadIdx.x;
    float p = pooled[f];
    sm[f]     = p * fcw[f * 2 + 0];
    sm[f + F] = p * fcw[f * 2 + 1];
    __syncthreads();
    for (int off = 64; off > 0; off >>= 1) {
        if (f < off) {
            sm[f]     += sm[f + off];
            sm[F + f] += sm[F + f + off];
        }
        __syncthreads();
    }
    if (f == 0) {
        out[0] = sm[0] + fcb[0];
        out[1] = sm[F] + fcb[1];
    }
}

extern "C" void kernel_launch(void* const* d_in, const int* in_sizes, int n_in,
                              void* d_out, int out_size, void* d_ws, size_t ws_size,
                              hipStream_t stream) {
    const float* x   = (const float*)d_in[0];
    const int*   ei  = (const int*)  d_in[1];
    const float* W1  = (const float*)d_in[2];
    const float* b1  = (const float*)d_in[3];
    const float* W2  = (const float*)d_in[4];
    const float* b2  = (const float*)d_in[5];
    const float* W3  = (const float*)d_in[6];
    const float* b3  = (const float*)d_in[7];
    const float* fcw = (const float*)d_in[8];
    const float* fcb = (const float*)d_in[9];
    float* out = (float*)d_out;

    const int n = in_sizes[0] / F;     // 100000
    const int e = in_sizes[1] / 2;     // 1600000
    const int* src = ei;
    const int* dst = ei + e;

    // workspace layout (all chunks multiple-of-4 floats => 16B aligned)
    float* ws     = (float*)d_ws;
    float* dinv   = ws;                         // n
    float* pooled = dinv + n;                   // 128
    int*   rowptr = (int*)(pooled + 128);       // n+4 (padded)
    int*   cnt    = rowptr + (n + 4);           // n   (also cursor)
    int*   bsum   = cnt + n;                    // 2048
    int*   col    = bsum + 2048;                // e
    float* enorm  = (float*)(col + e);          // e
    float* bufA   = enorm + e;                  // n*F
    float* bufB   = bufA + (size_t)n * F;       // n*F

    const int BT = 256;
    dim3 blk(BT);
    int gN    = (n + BT - 1) / BT;
    int gE    = (e + BT - 1) / BT;
    int gAgg  = (n + 7) / 8;
    int gMM   = (n + MM_ROWS - 1) / MM_ROWS;          // 6250
    int nbScan = (n + SCAN_CHUNK - 1) / SCAN_CHUNK;   // 98

    // ---- CSR build ----
    k_zero_int<<<gN, blk, 0, stream>>>(cnt, n);
    k_hist    <<<gE, blk, 0, stream>>>(dst, cnt, e);
    k_rsqrt   <<<gN, blk, 0, stream>>>(cnt, dinv, n);
    k_scan1   <<<nbScan, blk, 0, stream>>>(cnt, rowptr, bsum, n);
    k_scan2   <<<1, dim3(128), 0, stream>>>(bsum, nbScan);
    k_scan3   <<<nbScan, blk, 0, stream>>>(rowptr, bsum, n, e);
    k_zero_int<<<gN, blk, 0, stream>>>(cnt, n);      // reuse as cursor
    k_fill    <<<gE, blk, 0, stream>>>(src, dst, rowptr, cnt, dinv, col, enorm, e);

    // ---- 3 GCN layers ----
    const float* layer_in = x;
    const float* Ws[3] = {W1, W2, W3};
    const float* bs[3] = {b1, b2, b3};
    for (int l = 0; l < 3; ++l) {
        k_matmul16<<<gMM, blk, 0, stream>>>(layer_in, Ws[l], bufB, n);
        k_aggregate<<<gAgg, blk, 0, stream>>>((const float4*)bufB, rowptr, col, enorm,
                                              dinv, (const float4*)bs[l],
                                              (float4*)bufA, n);
        layer_in = bufA;
    }

    // ---- mean pool + FC ----
    k_zero128<<<1, dim3(F), 0, stream>>>(pooled);
    k_pool   <<<512, blk, 0, stream>>>(bufA, pooled, n, 1.0f / (float)n);
    k_fc     <<<1, dim3(F), 0, stream>>>(pooled, fcw, fcb, out);
}

// Round 4
// 743.832 us; speedup vs baseline: 18.2790x; 1.2477x over previous
//
#include <hip/hip_runtime.h>
#include <hip/hip_bf16.h>

#define F 128          // feature dim
#define F4 32          // feature dim in float4
#define SCAN_CHUNK 1024
#define MM_ROWS 32     // rows per matmul block

// ---------- zero int buffer ----------
__global__ void k_zero_int(int* p, int n) {
    int i = blockIdx.x * blockDim.x + threadIdx.x;
    if (i < n) p[i] = 0;
}

// ---------- histogram of dst ----------
__global__ void k_hist(const int* __restrict__ dst, int* cnt, int e) {
    int i = blockIdx.x * blockDim.x + threadIdx.x;
    if (i < e) atomicAdd(&cnt[dst[i]], 1);
}

// ---------- dinv[v] = 1/sqrt(cnt[v] + 1)  (self-loop) ----------
__global__ void k_rsqrt(const int* __restrict__ cnt, float* dinv, int n) {
    int i = blockIdx.x * blockDim.x + threadIdx.x;
    if (i < n) dinv[i] = 1.0f / sqrtf((float)cnt[i] + 1.0f);
}

// ---------- exclusive scan of cnt[0..n) -> rowptr[0..n), 3-phase ----------
__global__ void k_scan1(const int* __restrict__ cnt, int* rowptr, int* bsum, int n) {
    __shared__ int s[SCAN_CHUNK];
    int base = blockIdx.x * SCAN_CHUNK;
    int tid = threadIdx.x;
    for (int t = tid; t < SCAN_CHUNK; t += 256)
        s[t] = (base + t < n) ? cnt[base + t] : 0;
    __syncthreads();
    for (int off = 1; off < SCAN_CHUNK; off <<= 1) {
        int v0 = (tid       >= off) ? s[tid       - off] : 0;
        int v1 = (tid + 256 >= off) ? s[tid + 256 - off] : 0;
        int v2 = (tid + 512 >= off) ? s[tid + 512 - off] : 0;
        int v3 = (tid + 768 >= off) ? s[tid + 768 - off] : 0;
        __syncthreads();
        s[tid      ] += v0;
        s[tid + 256] += v1;
        s[tid + 512] += v2;
        s[tid + 768] += v3;
        __syncthreads();
    }
    for (int t = tid; t < SCAN_CHUNK; t += 256)
        if (base + t < n) rowptr[base + t] = s[t] - cnt[base + t];
    if (tid == 0) bsum[blockIdx.x] = s[SCAN_CHUNK - 1];
}

__global__ void k_scan2(int* bsum, int nb) {
    __shared__ int s[128];
    int tid = threadIdx.x;
    int v = (tid < nb) ? bsum[tid] : 0;
    s[tid] = v;
    __syncthreads();
    for (int off = 1; off < 128; off <<= 1) {
        int u = (tid >= off) ? s[tid - off] : 0;
        __syncthreads();
        s[tid] += u;
        __syncthreads();
    }
    if (tid < nb) bsum[tid] = s[tid] - v;   // exclusive
}

__global__ void k_scan3(int* rowptr, const int* __restrict__ bsum, int n, int e) {
    int base = blockIdx.x * SCAN_CHUNK;
    int add = bsum[blockIdx.x];
    for (int t = threadIdx.x; t < SCAN_CHUNK; t += 256)
        if (base + t < n) rowptr[base + t] += add;
    if (blockIdx.x == 0 && threadIdx.x == 0) rowptr[n] = e;
}

// ---------- fill CSR: col (src ids) + per-edge norm, bucketed by dst ----------
__global__ void k_fill(const int* __restrict__ src, const int* __restrict__ dst,
                       const int* __restrict__ rowptr, int* cursor,
                       const float* __restrict__ dinv,
                       int* col, float* enorm, int e) {
    int i = blockIdx.x * blockDim.x + threadIdx.x;
    if (i >= e) return;
    int d = dst[i];
    int s = src[i];
    int pos = rowptr[d] + atomicAdd(&cursor[d], 1);
    col[pos] = s;
    enorm[pos] = dinv[s] * dinv[d];
}

// ---------- dense matmul: H[n,128](bf16) = X[n,128](f32) @ W[128,128](f32) ----------
// 32 rows/block, 256 threads; thread = 8 rows x 2 cols (j, j+64).
// Per k-step of 4: 64 FMA vs 8 ds_read_b128 -> VALU-bound, no spill.
__global__ __launch_bounds__(256, 4)
void k_matmul32(const float* __restrict__ X, const float* __restrict__ W,
                __hip_bfloat16* __restrict__ H, int n) {
    __shared__ float xs[MM_ROWS][F];   // 16 KB
    int row0 = blockIdx.x * MM_ROWS;
    int tid = threadIdx.x;

    bool full = (row0 + MM_ROWS <= n);
    if (full) {
        const float4* X4 = (const float4*)(X + (size_t)row0 * F);
        float4* xs4 = (float4*)xs;
        xs4[tid]       = X4[tid];
        xs4[tid + 256] = X4[tid + 256];
        xs4[tid + 512] = X4[tid + 512];
        xs4[tid + 768] = X4[tid + 768];
    } else {
        for (int t = tid; t < MM_ROWS * F; t += 256) {
            int r = t >> 7, c = t & (F - 1);
            xs[r][c] = (row0 + r < n) ? X[(size_t)(row0 + r) * F + c] : 0.f;
        }
    }
    __syncthreads();

    int cj = tid & 63;          // columns cj and cj+64
    int rbase = (tid >> 6) * 8; // 0,8,16,24
    float acc0[8] = {0,0,0,0,0,0,0,0};
    float acc1[8] = {0,0,0,0,0,0,0,0};

    for (int k = 0; k < F; k += 4) {
        const float* Wk = W + (size_t)k * F;
        float wa0 = Wk[cj],         wb0 = Wk[cj + 64];
        float wa1 = Wk[F + cj],     wb1 = Wk[F + cj + 64];
        float wa2 = Wk[2 * F + cj], wb2 = Wk[2 * F + cj + 64];
        float wa3 = Wk[3 * F + cj], wb3 = Wk[3 * F + cj + 64];
#pragma unroll
        for (int r = 0; r < 8; ++r) {
            float4 xv = *(const float4*)&xs[rbase + r][k];   // wave-broadcast
            acc0[r] = fmaf(xv.x, wa0, acc0[r]);
            acc0[r] = fmaf(xv.y, wa1, acc0[r]);
            acc0[r] = fmaf(xv.z, wa2, acc0[r]);
            acc0[r] = fmaf(xv.w, wa3, acc0[r]);
            acc1[r] = fmaf(xv.x, wb0, acc1[r]);
            acc1[r] = fmaf(xv.y, wb1, acc1[r]);
            acc1[r] = fmaf(xv.z, wb2, acc1[r]);
            acc1[r] = fmaf(xv.w, wb3, acc1[r]);
        }
    }

#pragma unroll
    for (int r = 0; r < 8; ++r) {
        int row = row0 + rbase + r;
        if (full || row < n) {
            H[(size_t)row * F + cj]      = __float2bfloat16(acc0[r]);
            H[(size_t)row * F + cj + 64] = __float2bfloat16(acc1[r]);
        }
    }
}

// ---------- fused aggregate: out = relu(selfloop + gather + bias), bf16 H ----------
// 8 nodes per 256-thread block, 32 lanes per node, ushort4 (4 bf16) per lane
__device__ inline float4 bf4_to_f4(ushort4 q) {
    float4 f;
    f.x = __uint_as_float((unsigned)q.x << 16);
    f.y = __uint_as_float((unsigned)q.y << 16);
    f.z = __uint_as_float((unsigned)q.z << 16);
    f.w = __uint_as_float((unsigned)q.w << 16);
    return f;
}

__global__ void k_aggregate(const ushort4* __restrict__ Hq,   // [n*32]
                            const int* __restrict__ rowptr,
                            const int* __restrict__ col,
                            const float* __restrict__ enorm,
                            const float* __restrict__ dinv,
                            const float4* __restrict__ b4,
                            float4* __restrict__ out4, int n) {
    int v = blockIdx.x * 8 + (threadIdx.x >> 5);
    int lane = threadIdx.x & 31;
    if (v >= n) return;
    float dv = dinv[v];
    float sl = dv * dv;
    float4 acc = bf4_to_f4(Hq[(size_t)v * F4 + lane]);
    acc.x *= sl; acc.y *= sl; acc.z *= sl; acc.w *= sl;

    int beg = rowptr[v], end = rowptr[v + 1];
    int j = beg;
    for (; j + 1 < end; j += 2) {
        int s0 = col[j],     s1 = col[j + 1];
        float w0 = enorm[j], w1 = enorm[j + 1];
        ushort4 q0 = Hq[(size_t)s0 * F4 + lane];
        ushort4 q1 = Hq[(size_t)s1 * F4 + lane];
        float4 h0 = bf4_to_f4(q0);
        float4 h1 = bf4_to_f4(q1);
        acc.x = fmaf(h0.x, w0, acc.x);
        acc.y = fmaf(h0.y, w0, acc.y);
        acc.z = fmaf(h0.z, w0, acc.z);
        acc.w = fmaf(h0.w, w0, acc.w);
        acc.x = fmaf(h1.x, w1, acc.x);
        acc.y = fmaf(h1.y, w1, acc.y);
        acc.z = fmaf(h1.z, w1, acc.z);
        acc.w = fmaf(h1.w, w1, acc.w);
    }
    if (j < end) {
        int s0 = col[j];
        float w0 = enorm[j];
        float4 h0 = bf4_to_f4(Hq[(size_t)s0 * F4 + lane]);
        acc.x = fmaf(h0.x, w0, acc.x);
        acc.y = fmaf(h0.y, w0, acc.y);
        acc.z = fmaf(h0.z, w0, acc.z);
        acc.w = fmaf(h0.w, w0, acc.w);
    }

    float4 bb = b4[lane];
    acc.x = fmaxf(acc.x + bb.x, 0.f);
    acc.y = fmaxf(acc.y + bb.y, 0.f);
    acc.z = fmaxf(acc.z + bb.z, 0.f);
    acc.w = fmaxf(acc.w + bb.w, 0.f);
    out4[(size_t)v * F4 + lane] = acc;
}

// ---------- mean pool ----------
__global__ void k_zero128(float* p) { p[threadIdx.x] = 0.f; }

__global__ void k_pool(const float* __restrict__ H, float* pooled, int n, float inv_n) {
    int f = threadIdx.x & (F - 1);
    int rowoff = threadIdx.x >> 7;
    float s = 0.f;
    for (int row = blockIdx.x * 2 + rowoff; row < n; row += gridDim.x * 2)
        s += H[(size_t)row * F + f];
    __shared__ float sm[256];
    sm[threadIdx.x] = s;
    __syncthreads();
    if (threadIdx.x < F)
        atomicAdd(&pooled[f], (sm[threadIdx.x] + sm[threadIdx.x + F]) * inv_n);
}

// ---------- final FC ----------
__global__ void k_fc(const float* __restrict__ pooled, const float* __restrict__ fcw,
                     const float* __restrict__ fcb, float* out) {
    __shared__ float sm[2 * F];
    int f = threadIdx.x;
    float p = pooled[f];
    sm[f]     = p * fcw[f * 2 + 0];
    sm[f + F] = p * fcw[f * 2 + 1];
    __syncthreads();
    for (int off = 64; off > 0; off >>= 1) {
        if (f < off) {
            sm[f]     += sm[f + off];
            sm[F + f] += sm[F + f + off];
        }
        __syncthreads();
    }
    if (f == 0) {
        out[0] = sm[0] + fcb[0];
        out[1] = sm[F] + fcb[1];
    }
}

extern "C" void kernel_launch(void* const* d_in, const int* in_sizes, int n_in,
                              void* d_out, int out_size, void* d_ws, size_t ws_size,
                              hipStream_t stream) {
    const float* x   = (const float*)d_in[0];
    const int*   ei  = (const int*)  d_in[1];
    const float* W1  = (const float*)d_in[2];
    const float* b1  = (const float*)d_in[3];
    const float* W2  = (const float*)d_in[4];
    const float* b2  = (const float*)d_in[5];
    const float* W3  = (const float*)d_in[6];
    const float* b3  = (const float*)d_in[7];
    const float* fcw = (const float*)d_in[8];
    const float* fcb = (const float*)d_in[9];
    float* out = (float*)d_out;

    const int n = in_sizes[0] / F;     // 100000
    const int e = in_sizes[1] / 2;     // 1600000
    const int* src = ei;
    const int* dst = ei + e;

    // workspace layout (16B-aligned chunks)
    float* ws     = (float*)d_ws;
    float* dinv   = ws;                         // n
    float* pooled = dinv + n;                   // 128
    int*   rowptr = (int*)(pooled + 128);       // n+4 (padded)
    int*   cnt    = rowptr + (n + 4);           // n   (also cursor)
    int*   bsum   = cnt + n;                    // 2048
    int*   col    = bsum + 2048;                // e
    float* enorm  = (float*)(col + e);          // e
    __hip_bfloat16* bufB = (__hip_bfloat16*)(enorm + e);   // n*F bf16
    float* bufA   = (float*)(bufB + (size_t)n * F);        // n*F f32

    const int BT = 256;
    dim3 blk(BT);
    int gN    = (n + BT - 1) / BT;
    int gE    = (e + BT - 1) / BT;
    int gAgg  = (n + 7) / 8;
    int gMM   = (n + MM_ROWS - 1) / MM_ROWS;          // 3125
    int nbScan = (n + SCAN_CHUNK - 1) / SCAN_CHUNK;   // 98

    // ---- CSR build ----
    k_zero_int<<<gN, blk, 0, stream>>>(cnt, n);
    k_hist    <<<gE, blk, 0, stream>>>(dst, cnt, e);
    k_rsqrt   <<<gN, blk, 0, stream>>>(cnt, dinv, n);
    k_scan1   <<<nbScan, blk, 0, stream>>>(cnt, rowptr, bsum, n);
    k_scan2   <<<1, dim3(128), 0, stream>>>(bsum, nbScan);
    k_scan3   <<<nbScan, blk, 0, stream>>>(rowptr, bsum, n, e);
    k_zero_int<<<gN, blk, 0, stream>>>(cnt, n);      // reuse as cursor
    k_fill    <<<gE, blk, 0, stream>>>(src, dst, rowptr, cnt, dinv, col, enorm, e);

    // ---- 3 GCN layers ----
    const float* layer_in = x;
    const float* Ws[3] = {W1, W2, W3};
    const float* bs[3] = {b1, b2, b3};
    for (int l = 0; l < 3; ++l) {
        k_matmul32<<<gMM, blk, 0, stream>>>(layer_in, Ws[l], bufB, n);
        k_aggregate<<<gAgg, blk, 0, stream>>>((const ushort4*)bufB, rowptr, col, enorm,
                                              dinv, (const float4*)bs[l],
                                              (float4*)bufA, n);
        layer_in = bufA;
    }

    // ---- mean pool + FC ----
    k_zero128<<<1, dim3(F), 0, stream>>>(pooled);
    k_pool   <<<512, blk, 0, stream>>>(bufA, pooled, n, 1.0f / (float)n);
    k_fc     <<<1, dim3(F), 0, stream>>>(pooled, fcw, fcb, out);
}

// Round 5
// 667.113 us; speedup vs baseline: 20.3811x; 1.1150x over previous
//
#include <hip/hip_runtime.h>
#include <hip/hip_bf16.h>

#define F 128          // feature dim
#define F4 32          // feature dim in ushort4/float4 quads
#define SCAN_CHUNK 1024

typedef __attribute__((ext_vector_type(8))) short bf16x8;
typedef __attribute__((ext_vector_type(4))) float f32x4;

static __device__ inline unsigned short f2bf(float f) {
    __hip_bfloat16 b = __float2bfloat16(f);
    return *(unsigned short*)&b;
}

__device__ inline float4 bf4_to_f4(ushort4 q) {
    float4 f;
    f.x = __uint_as_float((unsigned)q.x << 16);
    f.y = __uint_as_float((unsigned)q.y << 16);
    f.z = __uint_as_float((unsigned)q.z << 16);
    f.w = __uint_as_float((unsigned)q.w << 16);
    return f;
}

// ---------- zero int buffer ----------
__global__ void k_zero_int(int* p, int n) {
    int i = blockIdx.x * blockDim.x + threadIdx.x;
    if (i < n) p[i] = 0;
}

// ---------- histogram of dst ----------
__global__ void k_hist(const int* __restrict__ dst, int* cnt, int e) {
    int i = blockIdx.x * blockDim.x + threadIdx.x;
    if (i < e) atomicAdd(&cnt[dst[i]], 1);
}

// ---------- dinv[v] = 1/sqrt(cnt[v] + 1)  (self-loop) ----------
__global__ void k_rsqrt(const int* __restrict__ cnt, float* dinv, int n) {
    int i = blockIdx.x * blockDim.x + threadIdx.x;
    if (i < n) dinv[i] = 1.0f / sqrtf((float)cnt[i] + 1.0f);
}

// ---------- exclusive scan of cnt[0..n) -> rowptr[0..n) ----------
__global__ void k_scan1(const int* __restrict__ cnt, int* rowptr, int* bsum, int n) {
    __shared__ int s[SCAN_CHUNK];
    int base = blockIdx.x * SCAN_CHUNK;
    int tid = threadIdx.x;
    for (int t = tid; t < SCAN_CHUNK; t += 256)
        s[t] = (base + t < n) ? cnt[base + t] : 0;
    __syncthreads();
    for (int off = 1; off < SCAN_CHUNK; off <<= 1) {
        int v0 = (tid       >= off) ? s[tid       - off] : 0;
        int v1 = (tid + 256 >= off) ? s[tid + 256 - off] : 0;
        int v2 = (tid + 512 >= off) ? s[tid + 512 - off] : 0;
        int v3 = (tid + 768 >= off) ? s[tid + 768 - off] : 0;
        __syncthreads();
        s[tid      ] += v0;
        s[tid + 256] += v1;
        s[tid + 512] += v2;
        s[tid + 768] += v3;
        __syncthreads();
    }
    for (int t = tid; t < SCAN_CHUNK; t += 256)
        if (base + t < n) rowptr[base + t] = s[t] - cnt[base + t];
    if (tid == 0) bsum[blockIdx.x] = s[SCAN_CHUNK - 1];
}

__global__ void k_scan2(int* bsum, int nb) {
    __shared__ int s[128];
    int tid = threadIdx.x;
    int v = (tid < nb) ? bsum[tid] : 0;
    s[tid] = v;
    __syncthreads();
    for (int off = 1; off < 128; off <<= 1) {
        int u = (tid >= off) ? s[tid - off] : 0;
        __syncthreads();
        s[tid] += u;
        __syncthreads();
    }
    if (tid < nb) bsum[tid] = s[tid] - v;   // exclusive
}

__global__ void k_scan3(int* rowptr, const int* __restrict__ bsum, int n, int e) {
    int base = blockIdx.x * SCAN_CHUNK;
    int add = bsum[blockIdx.x];
    for (int t = threadIdx.x; t < SCAN_CHUNK; t += 256)
        if (base + t < n) rowptr[base + t] += add;
    if (blockIdx.x == 0 && threadIdx.x == 0) rowptr[n] = e;
}

// ---------- fill CSR: col (src ids) only; norm computed in aggregate ----------
__global__ void k_fill(const int* __restrict__ src, const int* __restrict__ dst,
                       const int* __restrict__ rowptr, int* cursor,
                       int* col, int e) {
    int i = blockIdx.x * blockDim.x + threadIdx.x;
    if (i >= e) return;
    int d = dst[i];
    int pos = rowptr[d] + atomicAdd(&cursor[d], 1);
    col[pos] = src[i];
}

// ---------- fp32 -> bf16 convert ----------
__global__ void k_cvt(const float4* __restrict__ in, ushort4* __restrict__ out, int m) {
    int i = blockIdx.x * blockDim.x + threadIdx.x;
    if (i < m) {
        float4 v = in[i];
        ushort4 o;
        o.x = f2bf(v.x); o.y = f2bf(v.y); o.z = f2bf(v.z); o.w = f2bf(v.w);
        out[i] = o;
    }
}

// ---------- pack W (fp32 128x128) into MFMA B-fragment order, bf16 ----------
// B frag for 16x16x32: lane l holds B[k = kk*32 + (l>>4)*8 + i][col = ct*16 + (l&15)]
// Wp index = ((ct*4 + kk)*64 + l)*8 + i
__global__ void k_packW(const float* __restrict__ W, unsigned short* __restrict__ Wp) {
    int idx = blockIdx.x * 256 + threadIdx.x;   // 0..16383
    int i    = idx & 7;
    int lane = (idx >> 3) & 63;
    int kk   = (idx >> 9) & 3;
    int ct   = idx >> 11;
    int k = kk * 32 + ((lane >> 4) * 8) + i;
    int c = ct * 16 + (lane & 15);
    Wp[idx] = f2bf(W[k * F + c]);
}

// ---------- MFMA matmul: H[n,128](bf16) = X[n,128](bf16) @ W(packed bf16) ----------
// 64 rows/block (4 waves x 16 rows). A frags read directly from global (each
// X row read exactly once); B frags from packed Wp (L1-resident, 32 KB).
__global__ __launch_bounds__(256, 2)
void k_mm(const unsigned short* __restrict__ X,
          const unsigned short* __restrict__ Wp,
          unsigned short* __restrict__ H, int n) {
    int wave = threadIdx.x >> 6;
    int lane = threadIdx.x & 63;
    int row0 = blockIdx.x * 64 + wave * 16;
    if (row0 >= n) return;

    int arow = row0 + (lane & 15);
    if (arow >= n) arow = n - 1;   // clamp (stores guarded)
    const unsigned short* Abase = X + (size_t)arow * F + ((lane >> 4) * 8);

    f32x4 acc[8];
#pragma unroll
    for (int ct = 0; ct < 8; ++ct) acc[ct] = (f32x4){0.f, 0.f, 0.f, 0.f};

#pragma unroll
    for (int kk = 0; kk < 4; ++kk) {
        bf16x8 a = *(const bf16x8*)(Abase + kk * 32);
#pragma unroll
        for (int ct = 0; ct < 8; ++ct) {
            bf16x8 b = *(const bf16x8*)(Wp + (((size_t)(ct * 4 + kk) * 64 + lane) * 8));
            acc[ct] = __builtin_amdgcn_mfma_f32_16x16x32_bf16(a, b, acc[ct], 0, 0, 0);
        }
    }

    // C layout: col = lane&15, row = (lane>>4)*4 + r   [verified m89/m91]
    int orow0 = row0 + ((lane >> 4) * 4);
    int col = lane & 15;
#pragma unroll
    for (int ct = 0; ct < 8; ++ct) {
#pragma unroll
        for (int r = 0; r < 4; ++r) {
            int row = orow0 + r;
            if (row < n)
                H[(size_t)row * F + ct * 16 + col] = f2bf(acc[ct][r]);
        }
    }
}

// ---------- fused aggregate: out = relu(selfloop + gather + bias), bf16 in/out ----------
__global__ void k_aggregate(const ushort4* __restrict__ Hq,
                            const int* __restrict__ rowptr,
                            const int* __restrict__ col,
                            const float* __restrict__ dinv,
                            const float4* __restrict__ b4,
                            ushort4* __restrict__ outq, int n) {
    int v = blockIdx.x * 8 + (threadIdx.x >> 5);
    int lane = threadIdx.x & 31;
    if (v >= n) return;
    float dv = dinv[v];
    float4 acc = bf4_to_f4(Hq[(size_t)v * F4 + lane]);
    float sl = dv * dv;
    acc.x *= sl; acc.y *= sl; acc.z *= sl; acc.w *= sl;

    int beg = rowptr[v], end = rowptr[v + 1];
    int j = beg;
    for (; j + 3 < end; j += 4) {
        int s0 = col[j], s1 = col[j + 1], s2 = col[j + 2], s3 = col[j + 3];
        float w0 = dinv[s0] * dv, w1 = dinv[s1] * dv;
        float w2 = dinv[s2] * dv, w3 = dinv[s3] * dv;
        float4 h0 = bf4_to_f4(Hq[(size_t)s0 * F4 + lane]);
        float4 h1 = bf4_to_f4(Hq[(size_t)s1 * F4 + lane]);
        float4 h2 = bf4_to_f4(Hq[(size_t)s2 * F4 + lane]);
        float4 h3 = bf4_to_f4(Hq[(size_t)s3 * F4 + lane]);
        acc.x = fmaf(h0.x, w0, acc.x); acc.y = fmaf(h0.y, w0, acc.y);
        acc.z = fmaf(h0.z, w0, acc.z); acc.w = fmaf(h0.w, w0, acc.w);
        acc.x = fmaf(h1.x, w1, acc.x); acc.y = fmaf(h1.y, w1, acc.y);
        acc.z = fmaf(h1.z, w1, acc.z); acc.w = fmaf(h1.w, w1, acc.w);
        acc.x = fmaf(h2.x, w2, acc.x); acc.y = fmaf(h2.y, w2, acc.y);
        acc.z = fmaf(h2.z, w2, acc.z); acc.w = fmaf(h2.w, w2, acc.w);
        acc.x = fmaf(h3.x, w3, acc.x); acc.y = fmaf(h3.y, w3, acc.y);
        acc.z = fmaf(h3.z, w3, acc.z); acc.w = fmaf(h3.w, w3, acc.w);
    }
    for (; j < end; ++j) {
        int s0 = col[j];
        float w0 = dinv[s0] * dv;
        float4 h0 = bf4_to_f4(Hq[(size_t)s0 * F4 + lane]);
        acc.x = fmaf(h0.x, w0, acc.x); acc.y = fmaf(h0.y, w0, acc.y);
        acc.z = fmaf(h0.z, w0, acc.z); acc.w = fmaf(h0.w, w0, acc.w);
    }

    float4 bb = b4[lane];
    ushort4 o;
    o.x = f2bf(fmaxf(acc.x + bb.x, 0.f));
    o.y = f2bf(fmaxf(acc.y + bb.y, 0.f));
    o.z = f2bf(fmaxf(acc.z + bb.z, 0.f));
    o.w = f2bf(fmaxf(acc.w + bb.w, 0.f));
    outq[(size_t)v * F4 + lane] = o;
}

// ---------- mean pool (bf16 input) ----------
__global__ void k_zero128(float* p) { p[threadIdx.x] = 0.f; }

__global__ void k_pool(const ushort4* __restrict__ Hq, float* pooled, int n, float inv_n) {
    int q = threadIdx.x & 31;    // feature quad
    int r = threadIdx.x >> 5;    // 0..7
    float4 s = {0.f, 0.f, 0.f, 0.f};
    for (int row = blockIdx.x * 8 + r; row < n; row += gridDim.x * 8) {
        float4 h = bf4_to_f4(Hq[(size_t)row * F4 + q]);
        s.x += h.x; s.y += h.y; s.z += h.z; s.w += h.w;
    }
    __shared__ float4 sm[256];
    sm[threadIdx.x] = s;
    __syncthreads();
    if (threadIdx.x < 32) {
        float4 a = sm[threadIdx.x];
        for (int g = 1; g < 8; ++g) {
            float4 o = sm[g * 32 + threadIdx.x];
            a.x += o.x; a.y += o.y; a.z += o.z; a.w += o.w;
        }
        atomicAdd(&pooled[q * 4 + 0], a.x * inv_n);
        atomicAdd(&pooled[q * 4 + 1], a.y * inv_n);
        atomicAdd(&pooled[q * 4 + 2], a.z * inv_n);
        atomicAdd(&pooled[q * 4 + 3], a.w * inv_n);
    }
}

// ---------- final FC ----------
__global__ void k_fc(const float* __restrict__ pooled, const float* __restrict__ fcw,
                     const float* __restrict__ fcb, float* out) {
    __shared__ float sm[2 * F];
    int f = threadIdx.x;
    float p = pooled[f];
    sm[f]     = p * fcw[f * 2 + 0];
    sm[f + F] = p * fcw[f * 2 + 1];
    __syncthreads();
    for (int off = 64; off > 0; off >>= 1) {
        if (f < off) {
            sm[f]     += sm[f + off];
            sm[F + f] += sm[F + f + off];
        }
        __syncthreads();
    }
    if (f == 0) {
        out[0] = sm[0] + fcb[0];
        out[1] = sm[F] + fcb[1];
    }
}

extern "C" void kernel_launch(void* const* d_in, const int* in_sizes, int n_in,
                              void* d_out, int out_size, void* d_ws, size_t ws_size,
                              hipStream_t stream) {
    const float* x   = (const float*)d_in[0];
    const int*   ei  = (const int*)  d_in[1];
    const float* W1  = (const float*)d_in[2];
    const float* b1  = (const float*)d_in[3];
    const float* W2  = (const float*)d_in[4];
    const float* b2  = (const float*)d_in[5];
    const float* W3  = (const float*)d_in[6];
    const float* b3  = (const float*)d_in[7];
    const float* fcw = (const float*)d_in[8];
    const float* fcb = (const float*)d_in[9];
    float* out = (float*)d_out;

    const int n = in_sizes[0] / F;     // 100000
    const int e = in_sizes[1] / 2;     // 1600000
    const int* src = ei;
    const int* dst = ei + e;

    // workspace layout (floats; every chunk 16B-aligned)
    float* ws     = (float*)d_ws;
    float* dinv   = ws;                          // n
    float* pooled = dinv + n;                    // 128
    int*   rowptr = (int*)(pooled + 128);        // n+4
    int*   cnt    = rowptr + (n + 4);            // n (also cursor)
    int*   bsum   = cnt + n;                     // 2048
    int*   col    = bsum + 2048;                 // e
    unsigned short* Wp0 = (unsigned short*)(col + e);   // 16384 each, x3
    unsigned short* Wp1 = Wp0 + 16384;
    unsigned short* Wp2 = Wp1 + 16384;
    unsigned short* Xb  = Wp2 + 16384;           // n*F bf16 (layer input)
    unsigned short* Hb  = Xb + (size_t)n * F;    // n*F bf16 (matmul out)
    unsigned short* Ab  = Hb + (size_t)n * F;    // n*F bf16 (aggregate out)

    const int BT = 256;
    dim3 blk(BT);
    int gN    = (n + BT - 1) / BT;
    int gE    = (e + BT - 1) / BT;
    int gAgg  = (n + 7) / 8;
    int gMM   = (n + 63) / 64;                        // 1563
    int gCvt  = (n * F4 + BT - 1) / BT;
    int nbScan = (n + SCAN_CHUNK - 1) / SCAN_CHUNK;   // 98

    // ---- CSR build + normalization ----
    k_zero_int<<<gN, blk, 0, stream>>>(cnt, n);
    k_hist    <<<gE, blk, 0, stream>>>(dst, cnt, e);
    k_rsqrt   <<<gN, blk, 0, stream>>>(cnt, dinv, n);
    k_scan1   <<<nbScan, blk, 0, stream>>>(cnt, rowptr, bsum, n);
    k_scan2   <<<1, dim3(128), 0, stream>>>(bsum, nbScan);
    k_scan3   <<<nbScan, blk, 0, stream>>>(rowptr, bsum, n, e);
    k_zero_int<<<gN, blk, 0, stream>>>(cnt, n);      // reuse as cursor
    k_fill    <<<gE, blk, 0, stream>>>(src, dst, rowptr, cnt, col, e);

    // ---- input conversion + weight packing ----
    k_cvt  <<<gCvt, blk, 0, stream>>>((const float4*)x, (ushort4*)Xb, n * F4);
    k_packW<<<64, blk, 0, stream>>>(W1, Wp0);
    k_packW<<<64, blk, 0, stream>>>(W2, Wp1);
    k_packW<<<64, blk, 0, stream>>>(W3, Wp2);

    // ---- 3 GCN layers (bf16 activations, fp32 accumulate) ----
    const unsigned short* Wps[3] = {Wp0, Wp1, Wp2};
    const float* bs[3] = {b1, b2, b3};
    const unsigned short* cur = Xb;
    unsigned short* aggout[3] = {Ab, Xb, Ab};   // ping-pong (Xb free after layer1 mm)
    for (int l = 0; l < 3; ++l) {
        k_mm<<<gMM, blk, 0, stream>>>(cur, Wps[l], Hb, n);
        k_aggregate<<<gAgg, blk, 0, stream>>>((const ushort4*)Hb, rowptr, col,
                                              dinv, (const float4*)bs[l],
                                              (ushort4*)aggout[l], n);
        cur = aggout[l];
    }

    // ---- mean pool + FC ----
    k_zero128<<<1, dim3(F), 0, stream>>>(pooled);
    k_pool   <<<512, blk, 0, stream>>>((const ushort4*)Ab, pooled, n, 1.0f / (float)n);
    k_fc     <<<1, dim3(F), 0, stream>>>(pooled, fcw, fcb, out);
}